// Round 5
// baseline (250.521 us; speedup 1.0000x reference)
//
#include <hip/hip_runtime.h>

// Quantizer via bf16x3-split MFMA GEMM + exact-fp32 recheck of near-ties.
//   x: [16,64,32,32] fp32, embed: [64,8192] fp32
//   out[row][c] = embedT[argmax_j (f_row.e_j - ||e_j||^2/2)][c]
//
// R14: pipeline 5 kernels -> 3. R13 post-mortem: f16 screening made qdist fast
// but the wide margin fed a latency-pathological recheck (89us at 2.6% VALU).
// Revert to proven bf16-3product screening (thr 2e-3, ~0.1% flags) and attack
// the ~82us of non-qdist time instead:
//  - reduce_rows fused into qdist's tail (last-chunk-block-per-rowblock merges,
//    margin-tests, exact-quad rescores and writes out) -> overlapped with the
//    remaining qdist blocks, one launch + one latency-bound kernel deleted.
//  - gather_fix fused into recheck (32nd segment block per flagged row decodes
//    fkey and writes the row).

typedef __attribute__((ext_vector_type(8))) __bf16 bf16x8;
typedef __attribute__((ext_vector_type(4))) float f32x4;
typedef unsigned int u32;
typedef unsigned long long u64;

union frag_cast { f32x4 f; bf16x8 b; };
__device__ __forceinline__ bf16x8 as_bf16x8(f32x4 v) { frag_cast u; u.f = v; return u.b; }

#define N_ROWS  16384
#define E_DIM   64
#define N_EMBED 8192
#define NCHUNK  16
#define COLS_PER_BLOCK (N_EMBED / NCHUNK)   // 512
#define N_ST (COLS_PER_BLOCK / 64)          // 8 stages of 64 codes
#define ROWS_PER_BLOCK 512                  // 4 waves x 128 pixels
#define N_ROWBLK (N_ROWS / ROWS_PER_BLOCK)  // 32
#define NT 8                                // pixel-tiles per wave
#define MARGIN_THR 2e-3f

// ---- workspace byte offsets (~11.4 MB total)
#define WS_AH   0u              // pixel hi  [16384][64] bf16 (2 MB)
#define WS_AL   (2u << 20)      // pixel lo  (2 MB)
#define WS_B    (4u << 20)      // codes: 128 groups x [hi 64x128B | lo 64x128B] (2 MB)
#define WS_ET   (6u << 20)      // embedT fp32 [8192][64] (2 MB)
#define WS_BIAS (8u << 20)      // -||e_j||^2/2 (32 KB)
#define WS_CNT  (WS_BIAS + (32u << 10))     // [0]=nflag
#define WS_ARR  (WS_CNT + 64u)              // arrive[32] ints
#define WS_PB1  (WS_CNT + (4u << 10))       // 1 MB
#define WS_PI1  (WS_PB1 + (1u << 20))       // 1 MB
#define WS_PB2  (WS_PI1 + (1u << 20))       // 1 MB
#define WS_FLAG (WS_PB2 + (1u << 20))       // 64 KB
#define WS_FKEY (WS_FLAG + (64u << 10))     // 128 KB u64 keys
#define WS_DONE (WS_FKEY + (128u << 10))    // 64 KB per-row seg counters

__device__ __forceinline__ u32 f32_key(float s) {
    u32 u = __float_as_uint(s);
    return (u & 0x80000000u) ? ~u : (u | 0x80000000u);
}

__device__ __forceinline__ void async16(const void* g, void* l) {
    __builtin_amdgcn_global_load_lds(
        (const __attribute__((address_space(1))) void*)g,
        (__attribute__((address_space(3))) void*)l, 16, 0, 0);
}

// ---- K1: prep. Blocks 0..255: split x -> A_hi/A_lo [row][64] bf16.
//          Blocks 256..383: embedT fp32, bias, and swizzled interleaved code groups.
__global__ __launch_bounds__(256) void prep(
        const float* __restrict__ x, const float* __restrict__ embed, char* ws) {
    __shared__ float tile[64][65];
    __bf16* Ah = (__bf16*)(ws + WS_AH);
    __bf16* Al = (__bf16*)(ws + WS_AL);
    float*  eT = (float*)(ws + WS_ET);
    float*  bias = (float*)(ws + WS_BIAS);
    const int t = threadIdx.x;
    const int blk = blockIdx.x;

    if (blk < 256) {
        const int b = blk >> 4, p0 = (blk & 15) * 64;
        {
            const int c = t >> 2, seg = (t & 3) * 16;
            const float* src = x + b * 65536 + c * 1024 + p0 + seg;
#pragma unroll
            for (int i = 0; i < 16; ++i) tile[c][seg + i] = src[i];
        }
        __syncthreads();
        const int p = t >> 2, cq = (t & 3) * 16;
        const long row = b * 1024 + p0 + p;
        bf16x8 vh0, vh1, vl0, vl1;
#pragma unroll
        for (int i = 0; i < 16; ++i) {
            float f = tile[cq + i][p];
            __bf16 h = (__bf16)f;
            __bf16 l = (__bf16)(f - (float)h);
            if (i < 8) { vh0[i] = h; vl0[i] = l; }
            else       { vh1[i - 8] = h; vl1[i - 8] = l; }
        }
        *(bf16x8*)(Ah + row * 64 + cq) = vh0;
        *(bf16x8*)(Ah + row * 64 + cq + 8) = vh1;
        *(bf16x8*)(Al + row * 64 + cq) = vl0;
        *(bf16x8*)(Al + row * 64 + cq + 8) = vl1;
    } else {
        if (blk == 256) {
            if (t == 0) *(int*)(ws + WS_CNT) = 0;
            if (t < 32) ((int*)(ws + WS_ARR))[t] = 0;
        }
        const int g = blk - 256;             // 64-code group
        const int jbase = g * 64;
        char* Bg = ws + WS_B + (size_t)g * 16384;
        {
            const int c = t >> 2, seg = (t & 3) * 16;
            const float* src = embed + c * N_EMBED + jbase + seg;
#pragma unroll
            for (int i = 0; i < 16; ++i) tile[c][seg + i] = src[i];
        }
        __syncthreads();
        if (t < 64) {
            float s = 0.f;
#pragma unroll
            for (int c = 0; c < 64; ++c) { float v = tile[c][t]; s = fmaf(v, v, s); }
            bias[jbase + t] = -0.5f * s;
        }
        const int jl = t >> 2, cq = (t & 3) * 16;   // channels cq..cq+15
        bf16x8 vh0, vh1, vl0, vl1;
#pragma unroll
        for (int i = 0; i < 16; ++i) {
            float f = tile[cq + i][jl];
            eT[(long)(jbase + jl) * 64 + cq + i] = f;
            __bf16 h = (__bf16)f;
            __bf16 l = (__bf16)(f - (float)h);
            if (i < 8) { vh0[i] = h; vl0[i] = l; }
            else       { vh1[i - 8] = h; vl1[i - 8] = l; }
        }
        // granule-XOR swizzle: logical granule k (8 bf16) of code jl stored at
        // position k ^ (jl & 7). Keeps staging contiguous, LDS reads conflict-free.
        const int k0 = (cq >> 3), sw = jl & 7;
        __bf16* hi = (__bf16*)Bg + jl * 64;
        __bf16* lo = (__bf16*)(Bg + 8192) + jl * 64;
        *(bf16x8*)(hi + ((k0 ^ sw) * 8))       = vh0;
        *(bf16x8*)(hi + (((k0 + 1) ^ sw) * 8)) = vh1;
        *(bf16x8*)(lo + ((k0 ^ sw) * 8))       = vl0;
        *(bf16x8*)(lo + (((k0 + 1) ^ sw) * 8)) = vl1;
    }
}

// ---- K2: MFMA GEMM + running (quad-max top-2) argmax + fused row merge.
// grid 512 blocks (32 rowblk x 16 chunks), 256 thr, 2 blocks/CU.
// Last chunk-block per rowblock (arrival counter) merges the 16 chunks for its
// 512 rows, margin-tests, exact-quad rescores confident rows and writes out;
// near-ties get flagged for recheck.
__global__ __launch_bounds__(256, 2) void qdist(const char* __restrict__ ws_c, char* ws,
                                                const float* __restrict__ x,
                                                float* __restrict__ out) {
    __shared__ __align__(16) char smem[2][16384];
    __shared__ int isLast;
    const __bf16* Ah = (const __bf16*)(ws_c + WS_AH);
    const __bf16* Al = (const __bf16*)(ws_c + WS_AL);
    const char* Bws = ws_c + WS_B;
    const float* biasg = (const float*)(ws_c + WS_BIAS);
    float* pb1 = (float*)(ws + WS_PB1);
    int*   pi1 = (int*)(ws + WS_PI1);
    float* pb2 = (float*)(ws + WS_PB2);

    const int t = threadIdx.x;
    const int wv = t >> 6, lane = t & 63, ln = lane & 15, q = lane >> 4;
    const int rb = blockIdx.x >> 4, chunk = blockIdx.x & 15;
    const int row0 = rb * ROWS_PER_BLOCK;
    const int col0 = chunk * COLS_PER_BLOCK;
    const int g0 = col0 >> 6;               // first 64-code group of this chunk

    // resident pixel fragments (B-operand): 8 pixel-tiles x 2 K-halves x {hi,lo}
    f32x4 pfh[NT][2], pfl[NT][2];
#pragma unroll
    for (int nt = 0; nt < NT; ++nt) {
        long row = row0 + wv * 128 + nt * 16 + ln;
        long base = row * 64 + q * 8;
        pfh[nt][0] = *(const f32x4*)(Ah + base);
        pfh[nt][1] = *(const f32x4*)(Ah + base + 32);
        pfl[nt][0] = *(const f32x4*)(Al + base);
        pfl[nt][1] = *(const f32x4*)(Al + base + 32);
    }
    asm volatile("" :
        "+v"(pfh[0][0]), "+v"(pfh[0][1]), "+v"(pfh[1][0]), "+v"(pfh[1][1]),
        "+v"(pfh[2][0]), "+v"(pfh[2][1]), "+v"(pfh[3][0]), "+v"(pfh[3][1]),
        "+v"(pfh[4][0]), "+v"(pfh[4][1]), "+v"(pfh[5][0]), "+v"(pfh[5][1]),
        "+v"(pfh[6][0]), "+v"(pfh[6][1]), "+v"(pfh[7][0]), "+v"(pfh[7][1]));
    asm volatile("" :
        "+v"(pfl[0][0]), "+v"(pfl[0][1]), "+v"(pfl[1][0]), "+v"(pfl[1][1]),
        "+v"(pfl[2][0]), "+v"(pfl[2][1]), "+v"(pfl[3][0]), "+v"(pfl[3][1]),
        "+v"(pfl[4][0]), "+v"(pfl[4][1]), "+v"(pfl[5][0]), "+v"(pfl[5][1]),
        "+v"(pfl[6][0]), "+v"(pfl[6][1]), "+v"(pfl[7][0]), "+v"(pfl[7][1]));

    float b1[NT], b2[NT]; int iq[NT];
#pragma unroll
    for (int k = 0; k < NT; ++k) { b1[k] = -3.4e38f; b2[k] = -3.4e38f; iq[k] = 0; }

    // swizzled fragment read offsets: code cl=ct*16+ln; hi-K0 granule q^(ln&7)
    const int s7 = ln & 7;
    const int rdbase = ln * 128 + ((q ^ s7) << 4);

    auto issue = [&](int st) {
        const char* src = Bws + (size_t)(g0 + st) * 16384;
        char* dst = smem[st & 1];
#pragma unroll
        for (int s = 0; s < 4; ++s)
            async16(src + s * 4096 + wv * 1024 + lane * 16,
                    dst + s * 4096 + wv * 1024);
    };

    issue(0);
    for (int st = 0; st < N_ST; ++st) {
        __syncthreads();                 // own staging drained (vmcnt0 before barrier);
        if (st + 1 < N_ST) issue(st + 1);// all waves done reading buf[(st+1)&1]
        const char* buf = smem[st & 1];
        __builtin_amdgcn_s_setprio(1);
#pragma unroll
        for (int ct = 0; ct < 4; ++ct) {
            const int boff = ct * 2048 + rdbase;
            bf16x8 ah0 = *(const bf16x8*)(buf + boff);
            bf16x8 ah1 = *(const bf16x8*)(buf + (boff ^ 64));
            bf16x8 al0 = *(const bf16x8*)(buf + 8192 + boff);
            bf16x8 al1 = *(const bf16x8*)(buf + 8192 + (boff ^ 64));
            const int cbase = col0 + st * 64 + ct * 16;
            f32x4 bv = *(const f32x4*)(biasg + cbase + q * 4);  // bias for 4 codes
            const int jq = cbase + q * 4;
#pragma unroll
            for (int nt = 0; nt < NT; ++nt) {
                f32x4 acc = __builtin_amdgcn_mfma_f32_16x16x32_bf16(al0, as_bf16x8(pfh[nt][0]), bv, 0, 0, 0);
                acc = __builtin_amdgcn_mfma_f32_16x16x32_bf16(al1, as_bf16x8(pfh[nt][1]), acc, 0, 0, 0);
                acc = __builtin_amdgcn_mfma_f32_16x16x32_bf16(ah0, as_bf16x8(pfl[nt][0]), acc, 0, 0, 0);
                acc = __builtin_amdgcn_mfma_f32_16x16x32_bf16(ah1, as_bf16x8(pfl[nt][1]), acc, 0, 0, 0);
                acc = __builtin_amdgcn_mfma_f32_16x16x32_bf16(ah0, as_bf16x8(pfh[nt][0]), acc, 0, 0, 0);
                acc = __builtin_amdgcn_mfma_f32_16x16x32_bf16(ah1, as_bf16x8(pfh[nt][1]), acc, 0, 0, 0);
                // quad max (4 codes of one pixel)
                float mx = fmaxf(fmaxf(acc[0], acc[1]), fmaxf(acc[2], acc[3]));
                b2[nt] = fmaxf(b2[nt], fminf(b1[nt], mx));
                bool gt = mx > b1[nt];
                b1[nt] = fmaxf(b1[nt], mx);
                iq[nt] = gt ? jq : iq[nt];
            }
        }
        __builtin_amdgcn_s_setprio(0);
    }

    // merge across the 4 quads (same pixel lives in lanes ln, ln+16, ln+32, ln+48)
#pragma unroll
    for (int m = 16; m < 64; m <<= 1) {
#pragma unroll
        for (int nt = 0; nt < NT; ++nt) {
            float o1 = __shfl_xor(b1[nt], m);
            int   oi = __shfl_xor(iq[nt], m);
            float o2 = __shfl_xor(b2[nt], m);
            b2[nt] = fmaxf(fmaxf(fminf(b1[nt], o1), o2), b2[nt]);
            bool take = (o1 > b1[nt]) || (o1 == b1[nt] && oi < iq[nt]);
            if (take) { b1[nt] = o1; iq[nt] = oi; }
        }
    }
    if (q == 0) {
#pragma unroll
        for (int nt = 0; nt < NT; ++nt) {
            int pixel = row0 + wv * 128 + nt * 16 + ln;
            int o = chunk * N_ROWS + pixel;
            pb1[o] = b1[nt];
            pi1[o] = iq[nt];
            pb2[o] = b2[nt];
        }
    }

    // ---- fused tail: last chunk-block of this rowblock merges + finalizes ----
    __threadfence();                               // publish pb1/pi1/pb2
    if (t == 0)
        isLast = (atomicAdd((int*)(ws + WS_ARR) + rb, 1) == NCHUNK - 1) ? 1 : 0;
    __syncthreads();
    if (!isLast) return;
    __threadfence();                               // acquire others' publishes

    const float* eT = (const float*)(ws_c + WS_ET);
    int* flags = (int*)(ws + WS_FLAG);
    int* cnt = (int*)(ws + WS_CNT);
    u64* fkey = (u64*)(ws + WS_FKEY);
    int* done = (int*)(ws + WS_DONE);

#pragma unroll
    for (int rr = 0; rr < 2; ++rr) {
        const int row = row0 + rr * 256 + t;       // coalesced across lanes
        float m1 = pb1[row]; int mi = pi1[row]; float m2 = pb2[row];
#pragma unroll
        for (int ch = 1; ch < NCHUNK; ++ch) {
            float o1 = pb1[ch * N_ROWS + row];
            int   oi = pi1[ch * N_ROWS + row];
            float o2 = pb2[ch * N_ROWS + row];
            m2 = fmaxf(fmaxf(fminf(m1, o1), o2), m2);
            if (o1 > m1 || (o1 == m1 && oi < mi)) { m1 = o1; mi = oi; }
        }
        if (m1 - m2 < MARGIN_THR) {
            fkey[row] = 0ull;
            done[row] = 0;
            flags[atomicAdd(cnt, 1)] = row;        // out written by recheck's gather
        } else {
            // exact fp32 rescore of the winning quad, streaming (no xr[] array)
            const float* xb = x + (row >> 10) * 65536 + (row & 1023);
            const float* e0 = eT + (size_t)mi * 64;
            const float* e1 = e0 + 64;
            const float* e2 = e0 + 128;
            const float* e3 = e0 + 192;
            const float* bb = (const float*)(ws_c + WS_BIAS) + mi;
            float s0 = bb[0], s1 = bb[1], s2 = bb[2], s3 = bb[3];
#pragma unroll
            for (int c = 0; c < 64; ++c) {
                float xc = xb[c * 1024];
                s0 = fmaf(xc, e0[c], s0);
                s1 = fmaf(xc, e1[c], s1);
                s2 = fmaf(xc, e2[c], s2);
                s3 = fmaf(xc, e3[c], s3);
            }
            int bi = mi; float best = s0;
            if (s1 > best) { best = s1; bi = mi + 1; }
            if (s2 > best) { best = s2; bi = mi + 2; }
            if (s3 > best) { best = s3; bi = mi + 3; }
            const f32x4* src = (const f32x4*)(eT + (size_t)bi * 64);
            f32x4* dst = (f32x4*)(out + (size_t)row * 64);
#pragma unroll
            for (int v = 0; v < 16; ++v) dst[v] = src[v];
        }
    }
}

// ---- K3: exact fp32 rescan of flagged rows, 32 segment-blocks/row x 256 codes.
// The 32nd segment block per row decodes fkey and writes the output row.
__global__ __launch_bounds__(256) void recheck(const float* __restrict__ x, char* ws,
                                               float* __restrict__ out) {
    __shared__ float fl[64];
    __shared__ u64 red[256];
    __shared__ int sLast, sIdx;
    const float* eT = (const float*)(ws + WS_ET);
    const float* bias = (const float*)(ws + WS_BIAS);
    const int* flags = (const int*)(ws + WS_FLAG);
    const int n = *(const int*)(ws + WS_CNT);
    u64* fkey = (u64*)(ws + WS_FKEY);
    int* done = (int*)(ws + WS_DONE);
    const int t = threadIdx.x;

    for (int e = blockIdx.x; e < n * 32; e += gridDim.x) {
        const int row = flags[e >> 5];
        const int seg = e & 31;
        __syncthreads();                          // protect fl/red reuse
        if (t < 64) fl[t] = x[(row >> 10) * 65536 + t * 1024 + (row & 1023)];
        __syncthreads();
        float xr[64];
#pragma unroll
        for (int c = 0; c < 64; ++c) xr[c] = fl[c];

        const int j = seg * 256 + t;              // this thread's code
        const f32x4* ecd = (const f32x4*)(eT + (size_t)j * 64);
        f32x4 a0 = {0.f, 0.f, 0.f, 0.f}, a1 = a0, a2 = a0, a3 = a0;
#pragma unroll
        for (int v = 0; v < 4; ++v) {
            f32x4 e0 = ecd[v * 4 + 0], e1 = ecd[v * 4 + 1];
            f32x4 e2 = ecd[v * 4 + 2], e3 = ecd[v * 4 + 3];
#pragma unroll
            for (int k = 0; k < 4; ++k) {
                a0[k] = fmaf(xr[v * 16 + k],      e0[k], a0[k]);
                a1[k] = fmaf(xr[v * 16 + 4 + k],  e1[k], a1[k]);
                a2[k] = fmaf(xr[v * 16 + 8 + k],  e2[k], a2[k]);
                a3[k] = fmaf(xr[v * 16 + 12 + k], e3[k], a3[k]);
            }
        }
        f32x4 a01 = a0 + a1, a23 = a2 + a3;
        f32x4 as = a01 + a23;
        float s = bias[j] + ((as[0] + as[1]) + (as[2] + as[3]));

        red[t] = ((u64)f32_key(s) << 32) | (u32)(~(u32)j);
        __syncthreads();
        for (int off = 128; off; off >>= 1) {
            if (t < off) { u64 o = red[t + off]; if (o > red[t]) red[t] = o; }
            __syncthreads();
        }
        if (t == 0) {
            atomicMax(&fkey[row], red[0]);
            __threadfence();
            sLast = (atomicAdd(&done[row], 1) == 31) ? 1 : 0;
        }
        __syncthreads();
        if (sLast) {                               // block-uniform
            if (t == 0) {
                u64 k = atomicMax(&fkey[row], 0ull);   // coherent read
                sIdx = (int)(~(u32)(k & 0xffffffffull));
            }
            __syncthreads();
            if (t < 64) out[(size_t)row * 64 + t] = eT[(size_t)sIdx * 64 + t];
        }
        __syncthreads();
    }
}

extern "C" void kernel_launch(void* const* d_in, const int* in_sizes, int n_in,
                              void* d_out, int out_size, void* d_ws, size_t ws_size,
                              hipStream_t stream) {
    const float* x     = (const float*)d_in[0];
    const float* embed = (const float*)d_in[1];
    float* out = (float*)d_out;
    char* ws = (char*)d_ws;

    prep<<<384, 256, 0, stream>>>(x, embed, ws);
    qdist<<<N_ROWBLK * NCHUNK, 256, 0, stream>>>(ws, ws, x, out);
    recheck<<<2048, 256, 0, stream>>>(x, ws, out);
}

// Round 6
// 129.076 us; speedup vs baseline: 1.9409x; 1.9409x over previous
//
#include <hip/hip_runtime.h>

// Quantizer via bf16x3-split MFMA GEMM + exact-fp32 recheck of near-ties.
//   x: [16,64,32,32] fp32, embed: [64,8192] fp32
//   out[row][c] = embedT[argmax_j (f_row.e_j - ||e_j||^2/2)][c]
//
// R15: un-fuse R14 (tail-in-qdist concentrated divergent gathers on 32 solo
// blocks -> 185us). qdist reverted to proven R9 structure (~49us). The merge
// kernel is re-parallelized instead: 4 lanes per row (65536 thr, 4 waves/CU vs
// 1), lane-split chunk merge + one-code-per-lane exact quad rescore + shuffle
// argmax + cooperative out write. Divergent e-gathers: 4x fewer per lane, 4x
// more waves to hide them. recheck keeps R14's fused final write (4 launches).

typedef __attribute__((ext_vector_type(8))) __bf16 bf16x8;
typedef __attribute__((ext_vector_type(4))) float f32x4;
typedef unsigned int u32;
typedef unsigned long long u64;

union frag_cast { f32x4 f; bf16x8 b; };
__device__ __forceinline__ bf16x8 as_bf16x8(f32x4 v) { frag_cast u; u.f = v; return u.b; }

#define N_ROWS  16384
#define E_DIM   64
#define N_EMBED 8192
#define NCHUNK  16
#define COLS_PER_BLOCK (N_EMBED / NCHUNK)   // 512
#define N_ST (COLS_PER_BLOCK / 64)          // 8 stages of 64 codes
#define ROWS_PER_BLOCK 512                  // 4 waves x 128 pixels
#define N_ROWBLK (N_ROWS / ROWS_PER_BLOCK)  // 32
#define NT 8                                // pixel-tiles per wave
#define MARGIN_THR 2e-3f

// ---- workspace byte offsets (~11.4 MB total)
#define WS_AH   0u              // pixel hi  [16384][64] bf16 (2 MB)
#define WS_AL   (2u << 20)      // pixel lo  (2 MB)
#define WS_B    (4u << 20)      // codes: 128 groups x [hi 64x128B | lo 64x128B] (2 MB)
#define WS_ET   (6u << 20)      // embedT fp32 [8192][64] (2 MB)
#define WS_BIAS (8u << 20)      // -||e_j||^2/2 (32 KB)
#define WS_CNT  (WS_BIAS + (32u << 10))     // [0]=nflag
#define WS_PB1  (WS_CNT + (4u << 10))       // 1 MB
#define WS_PI1  (WS_PB1 + (1u << 20))       // 1 MB
#define WS_PB2  (WS_PI1 + (1u << 20))       // 1 MB
#define WS_FLAG (WS_PB2 + (1u << 20))       // 64 KB
#define WS_FKEY (WS_FLAG + (64u << 10))     // 128 KB u64 keys
#define WS_DONE (WS_FKEY + (128u << 10))    // 64 KB per-row seg counters

__device__ __forceinline__ u32 f32_key(float s) {
    u32 u = __float_as_uint(s);
    return (u & 0x80000000u) ? ~u : (u | 0x80000000u);
}

__device__ __forceinline__ void async16(const void* g, void* l) {
    __builtin_amdgcn_global_load_lds(
        (const __attribute__((address_space(1))) void*)g,
        (__attribute__((address_space(3))) void*)l, 16, 0, 0);
}

// ---- K1: prep. Blocks 0..255: split x -> A_hi/A_lo [row][64] bf16.
//          Blocks 256..383: embedT fp32, bias, and swizzled interleaved code groups.
__global__ __launch_bounds__(256) void prep(
        const float* __restrict__ x, const float* __restrict__ embed, char* ws) {
    __shared__ float tile[64][65];
    __bf16* Ah = (__bf16*)(ws + WS_AH);
    __bf16* Al = (__bf16*)(ws + WS_AL);
    float*  eT = (float*)(ws + WS_ET);
    float*  bias = (float*)(ws + WS_BIAS);
    const int t = threadIdx.x;
    const int blk = blockIdx.x;

    if (blk < 256) {
        const int b = blk >> 4, p0 = (blk & 15) * 64;
        {
            const int c = t >> 2, seg = (t & 3) * 16;
            const float* src = x + b * 65536 + c * 1024 + p0 + seg;
#pragma unroll
            for (int i = 0; i < 16; ++i) tile[c][seg + i] = src[i];
        }
        __syncthreads();
        const int p = t >> 2, cq = (t & 3) * 16;
        const long row = b * 1024 + p0 + p;
        bf16x8 vh0, vh1, vl0, vl1;
#pragma unroll
        for (int i = 0; i < 16; ++i) {
            float f = tile[cq + i][p];
            __bf16 h = (__bf16)f;
            __bf16 l = (__bf16)(f - (float)h);
            if (i < 8) { vh0[i] = h; vl0[i] = l; }
            else       { vh1[i - 8] = h; vl1[i - 8] = l; }
        }
        *(bf16x8*)(Ah + row * 64 + cq) = vh0;
        *(bf16x8*)(Ah + row * 64 + cq + 8) = vh1;
        *(bf16x8*)(Al + row * 64 + cq) = vl0;
        *(bf16x8*)(Al + row * 64 + cq + 8) = vl1;
    } else {
        if (blk == 256 && t == 0) *(int*)(ws + WS_CNT) = 0;
        const int g = blk - 256;             // 64-code group
        const int jbase = g * 64;
        char* Bg = ws + WS_B + (size_t)g * 16384;
        {
            const int c = t >> 2, seg = (t & 3) * 16;
            const float* src = embed + c * N_EMBED + jbase + seg;
#pragma unroll
            for (int i = 0; i < 16; ++i) tile[c][seg + i] = src[i];
        }
        __syncthreads();
        if (t < 64) {
            float s = 0.f;
#pragma unroll
            for (int c = 0; c < 64; ++c) { float v = tile[c][t]; s = fmaf(v, v, s); }
            bias[jbase + t] = -0.5f * s;
        }
        const int jl = t >> 2, cq = (t & 3) * 16;   // channels cq..cq+15
        bf16x8 vh0, vh1, vl0, vl1;
#pragma unroll
        for (int i = 0; i < 16; ++i) {
            float f = tile[cq + i][jl];
            eT[(long)(jbase + jl) * 64 + cq + i] = f;
            __bf16 h = (__bf16)f;
            __bf16 l = (__bf16)(f - (float)h);
            if (i < 8) { vh0[i] = h; vl0[i] = l; }
            else       { vh1[i - 8] = h; vl1[i - 8] = l; }
        }
        // granule-XOR swizzle: logical granule k (8 bf16) of code jl stored at
        // position k ^ (jl & 7). Keeps staging contiguous, LDS reads conflict-free.
        const int k0 = (cq >> 3), sw = jl & 7;
        __bf16* hi = (__bf16*)Bg + jl * 64;
        __bf16* lo = (__bf16*)(Bg + 8192) + jl * 64;
        *(bf16x8*)(hi + ((k0 ^ sw) * 8))       = vh0;
        *(bf16x8*)(hi + (((k0 + 1) ^ sw) * 8)) = vh1;
        *(bf16x8*)(lo + ((k0 ^ sw) * 8))       = vl0;
        *(bf16x8*)(lo + (((k0 + 1) ^ sw) * 8)) = vl1;
    }
}

// ---- K2: MFMA GEMM + running (quad-max top-2) argmax (proven R9 structure).
// grid 512 blocks (32 rowblk x 16 chunks), 256 thr, 2 blocks/CU.
__global__ __launch_bounds__(256, 2) void qdist(const char* __restrict__ ws_c, char* __restrict__ ws) {
    __shared__ __align__(16) char smem[2][16384];
    const __bf16* Ah = (const __bf16*)(ws_c + WS_AH);
    const __bf16* Al = (const __bf16*)(ws_c + WS_AL);
    const char* Bws = ws_c + WS_B;
    const float* biasg = (const float*)(ws_c + WS_BIAS);
    float* pb1 = (float*)(ws + WS_PB1);
    int*   pi1 = (int*)(ws + WS_PI1);
    float* pb2 = (float*)(ws + WS_PB2);

    const int t = threadIdx.x;
    const int wv = t >> 6, lane = t & 63, ln = lane & 15, q = lane >> 4;
    const int rb = blockIdx.x >> 4, chunk = blockIdx.x & 15;
    const int row0 = rb * ROWS_PER_BLOCK;
    const int col0 = chunk * COLS_PER_BLOCK;
    const int g0 = col0 >> 6;               // first 64-code group of this chunk

    // resident pixel fragments (B-operand): 8 pixel-tiles x 2 K-halves x {hi,lo}
    f32x4 pfh[NT][2], pfl[NT][2];
#pragma unroll
    for (int nt = 0; nt < NT; ++nt) {
        long row = row0 + wv * 128 + nt * 16 + ln;
        long base = row * 64 + q * 8;
        pfh[nt][0] = *(const f32x4*)(Ah + base);
        pfh[nt][1] = *(const f32x4*)(Ah + base + 32);
        pfl[nt][0] = *(const f32x4*)(Al + base);
        pfl[nt][1] = *(const f32x4*)(Al + base + 32);
    }
    asm volatile("" :
        "+v"(pfh[0][0]), "+v"(pfh[0][1]), "+v"(pfh[1][0]), "+v"(pfh[1][1]),
        "+v"(pfh[2][0]), "+v"(pfh[2][1]), "+v"(pfh[3][0]), "+v"(pfh[3][1]),
        "+v"(pfh[4][0]), "+v"(pfh[4][1]), "+v"(pfh[5][0]), "+v"(pfh[5][1]),
        "+v"(pfh[6][0]), "+v"(pfh[6][1]), "+v"(pfh[7][0]), "+v"(pfh[7][1]));
    asm volatile("" :
        "+v"(pfl[0][0]), "+v"(pfl[0][1]), "+v"(pfl[1][0]), "+v"(pfl[1][1]),
        "+v"(pfl[2][0]), "+v"(pfl[2][1]), "+v"(pfl[3][0]), "+v"(pfl[3][1]),
        "+v"(pfl[4][0]), "+v"(pfl[4][1]), "+v"(pfl[5][0]), "+v"(pfl[5][1]),
        "+v"(pfl[6][0]), "+v"(pfl[6][1]), "+v"(pfl[7][0]), "+v"(pfl[7][1]));

    float b1[NT], b2[NT]; int iq[NT];
#pragma unroll
    for (int k = 0; k < NT; ++k) { b1[k] = -3.4e38f; b2[k] = -3.4e38f; iq[k] = 0; }

    // swizzled fragment read offsets: code cl=ct*16+ln; hi-K0 granule q^(ln&7)
    const int s7 = ln & 7;
    const int rdbase = ln * 128 + ((q ^ s7) << 4);

    auto issue = [&](int st) {
        const char* src = Bws + (size_t)(g0 + st) * 16384;
        char* dst = smem[st & 1];
#pragma unroll
        for (int s = 0; s < 4; ++s)
            async16(src + s * 4096 + wv * 1024 + lane * 16,
                    dst + s * 4096 + wv * 1024);
    };

    issue(0);
    for (int st = 0; st < N_ST; ++st) {
        __syncthreads();                 // own staging drained (vmcnt0 before barrier);
        if (st + 1 < N_ST) issue(st + 1);// all waves done reading buf[(st+1)&1]
        const char* buf = smem[st & 1];
        __builtin_amdgcn_s_setprio(1);
#pragma unroll
        for (int ct = 0; ct < 4; ++ct) {
            const int boff = ct * 2048 + rdbase;
            bf16x8 ah0 = *(const bf16x8*)(buf + boff);
            bf16x8 ah1 = *(const bf16x8*)(buf + (boff ^ 64));
            bf16x8 al0 = *(const bf16x8*)(buf + 8192 + boff);
            bf16x8 al1 = *(const bf16x8*)(buf + 8192 + (boff ^ 64));
            const int cbase = col0 + st * 64 + ct * 16;
            f32x4 bv = *(const f32x4*)(biasg + cbase + q * 4);  // bias for 4 codes
            const int jq = cbase + q * 4;
#pragma unroll
            for (int nt = 0; nt < NT; ++nt) {
                f32x4 acc = __builtin_amdgcn_mfma_f32_16x16x32_bf16(al0, as_bf16x8(pfh[nt][0]), bv, 0, 0, 0);
                acc = __builtin_amdgcn_mfma_f32_16x16x32_bf16(al1, as_bf16x8(pfh[nt][1]), acc, 0, 0, 0);
                acc = __builtin_amdgcn_mfma_f32_16x16x32_bf16(ah0, as_bf16x8(pfl[nt][0]), acc, 0, 0, 0);
                acc = __builtin_amdgcn_mfma_f32_16x16x32_bf16(ah1, as_bf16x8(pfl[nt][1]), acc, 0, 0, 0);
                acc = __builtin_amdgcn_mfma_f32_16x16x32_bf16(ah0, as_bf16x8(pfh[nt][0]), acc, 0, 0, 0);
                acc = __builtin_amdgcn_mfma_f32_16x16x32_bf16(ah1, as_bf16x8(pfh[nt][1]), acc, 0, 0, 0);
                // quad max (4 codes of one pixel)
                float mx = fmaxf(fmaxf(acc[0], acc[1]), fmaxf(acc[2], acc[3]));
                b2[nt] = fmaxf(b2[nt], fminf(b1[nt], mx));
                bool gt = mx > b1[nt];
                b1[nt] = fmaxf(b1[nt], mx);
                iq[nt] = gt ? jq : iq[nt];
            }
        }
        __builtin_amdgcn_s_setprio(0);
    }

    // merge across the 4 quads (same pixel lives in lanes ln, ln+16, ln+32, ln+48)
#pragma unroll
    for (int m = 16; m < 64; m <<= 1) {
#pragma unroll
        for (int nt = 0; nt < NT; ++nt) {
            float o1 = __shfl_xor(b1[nt], m);
            int   oi = __shfl_xor(iq[nt], m);
            float o2 = __shfl_xor(b2[nt], m);
            b2[nt] = fmaxf(fmaxf(fminf(b1[nt], o1), o2), b2[nt]);
            bool take = (o1 > b1[nt]) || (o1 == b1[nt] && oi < iq[nt]);
            if (take) { b1[nt] = o1; iq[nt] = oi; }
        }
    }
    if (q == 0) {
#pragma unroll
        for (int nt = 0; nt < NT; ++nt) {
            int pixel = row0 + wv * 128 + nt * 16 + ln;
            int o = chunk * N_ROWS + pixel;
            pb1[o] = b1[nt];
            pi1[o] = iq[nt];
            pb2[o] = b2[nt];
        }
    }
}

// ---- K3: merge chunks per row, 4 lanes/row. Lane-split chunk merge + shuffle;
// confident rows: one-code-per-lane exact rescore + shuffle argmax + coop write.
// 256 blocks x 256 thr = 65536 threads (4 waves/CU).
__global__ __launch_bounds__(256) void reduce_rows(const float* __restrict__ x, char* ws,
                                                   float* __restrict__ out) {
    const float* pb1 = (const float*)(ws + WS_PB1);
    const int*   pi1 = (const int*)(ws + WS_PI1);
    const float* pb2 = (const float*)(ws + WS_PB2);
    const float* eT = (const float*)(ws + WS_ET);
    const float* bias = (const float*)(ws + WS_BIAS);
    int* flags = (int*)(ws + WS_FLAG);
    int* cnt = (int*)(ws + WS_CNT);
    u64* fkey = (u64*)(ws + WS_FKEY);
    int* done = (int*)(ws + WS_DONE);
    const int t = threadIdx.x;
    const int row = (blockIdx.x * 256 + t) >> 2;
    const int sub = t & 3;

    // per-lane merge over chunks sub*4 .. sub*4+3 (coalesced across the wave)
    float m1 = -3.4e38f, m2 = -3.4e38f; int mi = 0;
#pragma unroll
    for (int k = 0; k < 4; ++k) {
        const int ch = sub * 4 + k;
        float o1 = pb1[ch * N_ROWS + row];
        int   oi = pi1[ch * N_ROWS + row];
        float o2 = pb2[ch * N_ROWS + row];
        m2 = fmaxf(fmaxf(fminf(m1, o1), o2), m2);
        if (o1 > m1 || (o1 == m1 && oi < mi)) { m1 = o1; mi = oi; }
    }
    // merge across the 4 lanes of this row (xor masks 1,2 stay in-group)
#pragma unroll
    for (int m = 1; m < 4; m <<= 1) {
        float o1 = __shfl_xor(m1, m);
        int   oi = __shfl_xor(mi, m);
        float o2 = __shfl_xor(m2, m);
        m2 = fmaxf(fmaxf(fminf(m1, o1), o2), m2);
        bool take = (o1 > m1) || (o1 == m1 && oi < mi);
        if (take) { m1 = o1; mi = oi; }
    }

    if (m1 - m2 < MARGIN_THR) {
        if (sub == 0) {
            fkey[row] = 0ull;                  // any finite score key > 0
            done[row] = 0;
            flags[atomicAdd(cnt, 1)] = row;    // out written by recheck
        }
    } else {
        // exact fp32 rescore: lane sub scores code mi+sub (c ascending, 1 accum)
        const float* xb = x + (row >> 10) * 65536 + (row & 1023);
        const int j = mi + sub;
        const f32x4* ecd = (const f32x4*)(eT + (size_t)j * 64);
        float s = bias[j];
#pragma unroll
        for (int v = 0; v < 16; ++v) {
            f32x4 ev = ecd[v];
            s = fmaf(xb[(v * 4 + 0) * 1024], ev[0], s);
            s = fmaf(xb[(v * 4 + 1) * 1024], ev[1], s);
            s = fmaf(xb[(v * 4 + 2) * 1024], ev[2], s);
            s = fmaf(xb[(v * 4 + 3) * 1024], ev[3], s);
        }
        // argmax across the 4 lanes; tie -> lowest j
        float best = s; int bj = j;
#pragma unroll
        for (int m = 1; m < 4; m <<= 1) {
            float os = __shfl_xor(best, m);
            int   oj = __shfl_xor(bj, m);
            bool take = (os > best) || (os == best && oj < bj);
            if (take) { best = os; bj = oj; }
        }
        // cooperative row write: 4 lanes x 4 f32x4
        const f32x4* src = (const f32x4*)(eT + (size_t)bj * 64);
        f32x4* dst = (f32x4*)(out + (size_t)row * 64);
#pragma unroll
        for (int v = 0; v < 4; ++v) dst[v * 4 + sub] = src[v * 4 + sub];
    }
}

// ---- K4: exact fp32 rescan of flagged rows, 32 segment-blocks/row x 256 codes.
// The 32nd segment block per row decodes fkey and writes the output row.
__global__ __launch_bounds__(256) void recheck(const float* __restrict__ x, char* ws,
                                               float* __restrict__ out) {
    __shared__ float fl[64];
    __shared__ u64 red[256];
    __shared__ int sLast, sIdx;
    const float* eT = (const float*)(ws + WS_ET);
    const float* bias = (const float*)(ws + WS_BIAS);
    const int* flags = (const int*)(ws + WS_FLAG);
    const int n = *(const int*)(ws + WS_CNT);
    u64* fkey = (u64*)(ws + WS_FKEY);
    int* done = (int*)(ws + WS_DONE);
    const int t = threadIdx.x;

    for (int e = blockIdx.x; e < n * 32; e += gridDim.x) {
        const int row = flags[e >> 5];
        const int seg = e & 31;
        __syncthreads();                          // protect fl/red reuse
        if (t < 64) fl[t] = x[(row >> 10) * 65536 + t * 1024 + (row & 1023)];
        __syncthreads();
        float xr[64];
#pragma unroll
        for (int c = 0; c < 64; ++c) xr[c] = fl[c];

        const int j = seg * 256 + t;              // this thread's code
        const f32x4* ecd = (const f32x4*)(eT + (size_t)j * 64);
        f32x4 a0 = {0.f, 0.f, 0.f, 0.f}, a1 = a0, a2 = a0, a3 = a0;
#pragma unroll
        for (int v = 0; v < 4; ++v) {
            f32x4 e0 = ecd[v * 4 + 0], e1 = ecd[v * 4 + 1];
            f32x4 e2 = ecd[v * 4 + 2], e3 = ecd[v * 4 + 3];
#pragma unroll
            for (int k = 0; k < 4; ++k) {
                a0[k] = fmaf(xr[v * 16 + k],      e0[k], a0[k]);
                a1[k] = fmaf(xr[v * 16 + 4 + k],  e1[k], a1[k]);
                a2[k] = fmaf(xr[v * 16 + 8 + k],  e2[k], a2[k]);
                a3[k] = fmaf(xr[v * 16 + 12 + k], e3[k], a3[k]);
            }
        }
        f32x4 a01 = a0 + a1, a23 = a2 + a3;
        f32x4 as = a01 + a23;
        float s = bias[j] + ((as[0] + as[1]) + (as[2] + as[3]));

        red[t] = ((u64)f32_key(s) << 32) | (u32)(~(u32)j);
        __syncthreads();
        for (int off = 128; off; off >>= 1) {
            if (t < off) { u64 o = red[t + off]; if (o > red[t]) red[t] = o; }
            __syncthreads();
        }
        if (t == 0) {
            atomicMax(&fkey[row], red[0]);
            __threadfence();
            sLast = (atomicAdd(&done[row], 1) == 31) ? 1 : 0;
        }
        __syncthreads();
        if (sLast) {                               // block-uniform
            if (t == 0) {
                u64 k = atomicMax(&fkey[row], 0ull);   // coherent read
                sIdx = (int)(~(u32)(k & 0xffffffffull));
            }
            __syncthreads();
            if (t < 64) out[(size_t)row * 64 + t] = eT[(size_t)sIdx * 64 + t];
        }
        __syncthreads();
    }
}

extern "C" void kernel_launch(void* const* d_in, const int* in_sizes, int n_in,
                              void* d_out, int out_size, void* d_ws, size_t ws_size,
                              hipStream_t stream) {
    const float* x     = (const float*)d_in[0];
    const float* embed = (const float*)d_in[1];
    float* out = (float*)d_out;
    char* ws = (char*)d_ws;

    prep<<<384, 256, 0, stream>>>(x, embed, ws);
    qdist<<<N_ROWBLK * NCHUNK, 256, 0, stream>>>(ws, ws);
    reduce_rows<<<256, 256, 0, stream>>>(x, ws, out);
    recheck<<<2048, 256, 0, stream>>>(x, ws, out);
}